// Round 7
// baseline (692.469 us; speedup 1.0000x reference)
//
#include <hip/hip_runtime.h>
#include <hip/hip_bf16.h>
#include <stdint.h>

// LNLinearSigmoid: LayerNorm(x) @ W^T -> sigmoid
// Round 7: B (weights) read DIRECTLY from global into registers (L2-resident,
// perfectly coalesced 16-line gathers) -> LDS holds only A (64 KB, dbuf).
// LDS pipe drops below MFMA pipe. One barrier + counted vmcnt per K-tile.
// A-side keeps the proven zero-conflict XOR swizzle. ws >= 75.5 MB.

typedef __attribute__((ext_vector_type(4))) float f32x4;
typedef __attribute__((ext_vector_type(8))) __bf16 b16x8;

__device__ __forceinline__ void async16(void* lds_p, const void* g) {
  __builtin_amdgcn_global_load_lds(
      (const __attribute__((address_space(1))) void*)g,
      (__attribute__((address_space(3))) void*)lds_p, 16, 0, 0);
}

__device__ __forceinline__ unsigned short f2bf(float f) {
  uint32_t u = __float_as_uint(f);
  u += 0x7FFFu + ((u >> 16) & 1u);
  return (unsigned short)(u >> 16);
}

// ---------------- LN (blocks 0..16383) + W conv (blocks 16384..20479) ------
__global__ __launch_bounds__(256) void ln_wconv_kernel(
    const float* __restrict__ x, unsigned short* __restrict__ xn,
    const float* __restrict__ W, unsigned short* __restrict__ Wb) {
  const int t = threadIdx.x;
  if (blockIdx.x >= 16384) {
    const size_t i = (size_t)(blockIdx.x - 16384) * 256 + t;
    float4 v = ((const float4*)W)[i];
    ushort4 o;
    o.x = f2bf(v.x); o.y = f2bf(v.y); o.z = f2bf(v.z); o.w = f2bf(v.w);
    ((ushort4*)Wb)[i] = o;
    return;
  }
  const int row = blockIdx.x;
  const float4* xr = (const float4*)(x + (size_t)row * 2048);
  float4 a = xr[t];
  float4 b = xr[t + 256];
  float s = a.x + a.y + a.z + a.w + b.x + b.y + b.z + b.w;
  float q = a.x * a.x + a.y * a.y + a.z * a.z + a.w * a.w +
            b.x * b.x + b.y * b.y + b.z * b.z + b.w * b.w;
#pragma unroll
  for (int off = 32; off > 0; off >>= 1) {
    s += __shfl_down(s, off);
    q += __shfl_down(q, off);
  }
  __shared__ float red[8];
  const int w = t >> 6;
  if ((t & 63) == 0) { red[w] = s; red[4 + w] = q; }
  __syncthreads();
  s = red[0] + red[1] + red[2] + red[3];
  q = red[4] + red[5] + red[6] + red[7];
  const float mean = s * (1.0f / 2048.0f);
  const float var = fmaxf(q * (1.0f / 2048.0f) - mean * mean, 0.0f);
  const float scl = rsqrtf(var + 1e-5f);
  ushort4 o0, o1;
  o0.x = f2bf((a.x - mean) * scl);
  o0.y = f2bf((a.y - mean) * scl);
  o0.z = f2bf((a.z - mean) * scl);
  o0.w = f2bf((a.w - mean) * scl);
  o1.x = f2bf((b.x - mean) * scl);
  o1.y = f2bf((b.y - mean) * scl);
  o1.z = f2bf((b.z - mean) * scl);
  o1.w = f2bf((b.w - mean) * scl);
  ushort4* orow = (ushort4*)(xn + (size_t)row * 2048);
  orow[t] = o0;
  orow[t + 256] = o1;
}

// ---------------- 256x256 GEMM: A in LDS (dbuf), B in registers -----------
// LDS: buf*32768 + half(qm)*16384 + row*128. 1 barrier + VMC(8)/VMC(4)
// per K-tile. Issue order per tile t: [STG_A(t+1) x4 async16][LDG_B(t+1) x8]
// -> head VMC(8) drains A(t) (oldest 4 of 12), pre-MFMA VMC(4) drains B(t).
// aF (32 VGPR) WAR-refilled between S-halves; bF (32 VGPR) WAR-refilled
// inside qm1 clusters (bF[.][0] dead after qm1-S0, [.][1] after qm1-S1).

#define STG_A(BOFF, KT2)                                               \
  do {                                                                 \
    const char* s_ = pA + (size_t)(KT2) * 128;                         \
    char* d_ = lds + (BOFF) + tid * 16;                                \
    async16(d_, s_);                                                   \
    async16(d_ + 8192, s_ + (size_t)64 * 4096);                        \
    async16(d_ + 16384, s_ + (size_t)128 * 4096);                      \
    async16(d_ + 24576, s_ + (size_t)192 * 4096);                      \
  } while (0)

#define LDG_B_S(KT2, S)                                                \
  do {                                                                 \
    bF[0][S] = *(const b16x8*)(pBv + (size_t)(KT2) * 128 + (S) * 64);  \
    bF[1][S] = *(const b16x8*)(pBv + 65536 + (size_t)(KT2) * 128 + (S) * 64); \
    bF[2][S] = *(const b16x8*)(pBv + 524288 + (size_t)(KT2) * 128 + (S) * 64); \
    bF[3][S] = *(const b16x8*)(pBv + 589824 + (size_t)(KT2) * 128 + (S) * 64); \
  } while (0)

#define LDA_H(BOFF, HALF, S)                                           \
  do {                                                                 \
    _Pragma("unroll") for (int i_ = 0; i_ < 4; ++i_) {                 \
      const char* p_ = lds + (BOFF) + (HALF) * 16384 + abase + i_ * 2048; \
      aF[i_][S] = *(const b16x8*)(p_ + ((S) ? cs1 : cs0));             \
    }                                                                  \
  } while (0)

#define MFMA_C(QM, S)                                                  \
  do {                                                                 \
    __builtin_amdgcn_s_setprio(1);                                     \
    _Pragma("unroll") for (int i_ = 0; i_ < 4; ++i_) {                 \
      _Pragma("unroll") for (int n_ = 0; n_ < 4; ++n_) {               \
        acc[(QM) * 4 + i_][n_] = __builtin_amdgcn_mfma_f32_16x16x32_bf16( \
            aF[i_][S], bF[n_][S], acc[(QM) * 4 + i_][n_], 0, 0, 0);    \
      }                                                                \
    }                                                                  \
    __builtin_amdgcn_s_setprio(0);                                     \
  } while (0)

#define BARR                                                           \
  do {                                                                 \
    __builtin_amdgcn_s_barrier();                                      \
    asm volatile("" ::: "memory");                                     \
  } while (0)

#define LGKM0                                                          \
  do {                                                                 \
    asm volatile("s_waitcnt lgkmcnt(0)" ::: "memory");                 \
    __builtin_amdgcn_sched_barrier(0);                                 \
  } while (0)

#define LGKM4                                                          \
  do {                                                                 \
    asm volatile("s_waitcnt lgkmcnt(4)" ::: "memory");                 \
    __builtin_amdgcn_sched_barrier(0);                                 \
  } while (0)

#define SB0 __builtin_amdgcn_sched_barrier(0)
#define VMC(n) asm volatile("s_waitcnt vmcnt(" #n ")" ::: "memory")

// One K-tile: BC = current A buf byte-offset, BN_ = next, S2 = stage/load t+1
#define TILE(KT, BC, BN_, S2)                                          \
  do {                                                                 \
    BARR;                                                              \
    VMC(8); SB0;              /* A(t) landed (oldest 4) */             \
    LDA_H(BC, 0, 0); LDA_H(BC, 0, 1);                                  \
    if (S2) STG_A(BN_, (KT) + 1);                                      \
    LGKM0;                                                             \
    if (S2) { VMC(4); } else { VMC(0); }  /* B(t) in regs */           \
    SB0;                                                               \
    MFMA_C(0, 0);                                                      \
    SB0; LDA_H(BC, 1, 0); SB0;                                         \
    MFMA_C(0, 1);                                                      \
    SB0; LDA_H(BC, 1, 1);                                              \
    LGKM4;                                                             \
    MFMA_C(1, 0);                                                      \
    if (S2) { SB0; LDG_B_S((KT) + 1, 0); SB0; }                        \
    LGKM0;                                                             \
    MFMA_C(1, 1);                                                      \
    if (S2) { SB0; LDG_B_S((KT) + 1, 1); }                             \
  } while (0)

__global__ __launch_bounds__(512, 2) void gemm8p(
    const unsigned short* __restrict__ A, const unsigned short* __restrict__ B,
    float* __restrict__ C) {
  __shared__ __align__(16) char lds[65536];

  const int bid0 = blockIdx.x;                       // 512 blocks
  const int bid = (bid0 & 7) * 64 + (bid0 >> 3);     // XCD swizzle (512%8==0)
  const int bm = bid >> 3;                           // 0..63
  const int bn = bid & 7;                            // 0..7

  const int tid = threadIdx.x;
  const int w = tid >> 6, l = tid & 63;
  const int wr = w >> 2, wc = w & 3;
  const int fr = l & 15, fg = l >> 4;

  // A staging source (linear LDS dest, inverse-swizzled global source)
  const int arow = tid >> 3;
  const int swz = ((tid & 7) << 4) ^ ((arow & 7) << 4);
  const char* pA = (const char*)A + (size_t)(bm * 256 + arow) * 4096 + swz;

  // B direct-global lane base: row = bn*256 + wc*32 + fr (+qn*128 +j*16),
  // byte = row*4096 + fg*16 (+kt*128 +s*64). Offsets: j*16*4096=65536,
  // qn*128*4096=524288.
  const char* pBv =
      (const char*)B + (size_t)(bn * 256 + wc * 32 + fr) * 4096 + fg * 16;

  // A ds_read offsets (proven zero-conflict swizzle)
  const int cswz = (fg << 4) ^ ((fr & 7) << 4);
  const int cs0 = cswz, cs1 = cswz ^ 64;
  const int abase = (wr * 64 + fr) * 128;

  f32x4 acc[8][4] = {};
  b16x8 aF[4][2], bF[4][2];

  // prologue: B(0) -> regs, A(0) -> buf0, drain, align
  LDG_B_S(0, 0); LDG_B_S(0, 1);
  STG_A(0, 0);
  VMC(0);

#pragma unroll 1
  for (int it = 0; it < 16; ++it) {
    const int t0 = 2 * it, t1v = 2 * it + 1;
    TILE(t0, 0, 32768, 1);
    if (it < 15) {
      TILE(t1v, 32768, 0, 1);
    } else {
      TILE(t1v, 32768, 0, 0);
    }
  }

  // epilogue: sigmoid + store. C/D frag: row = fg*4 + r, col = fr.
  float* gC = C + (size_t)(bm * 256) * 2048 + bn * 256;
#pragma unroll
  for (int qm = 0; qm < 2; ++qm) {
#pragma unroll
    for (int i = 0; i < 4; ++i) {
#pragma unroll
      for (int qn = 0; qn < 2; ++qn) {
#pragma unroll
        for (int j = 0; j < 2; ++j) {
#pragma unroll
          for (int r = 0; r < 4; ++r) {
            const int row = qm * 128 + wr * 64 + i * 16 + fg * 4 + r;
            const int col = qn * 128 + wc * 32 + j * 16 + fr;
            const float y = acc[qm * 4 + i][qn * 2 + j][r];
            gC[(size_t)row * 2048 + col] =
                __builtin_amdgcn_rcpf(1.0f + __expf(-y));
          }
        }
      }
    }
  }
}

extern "C" void kernel_launch(void* const* d_in, const int* in_sizes, int n_in,
                              void* d_out, int out_size, void* d_ws, size_t ws_size,
                              hipStream_t stream) {
  const float* x = (const float*)d_in[0];
  const float* W = (const float*)d_in[1];
  float* out = (float*)d_out;

  unsigned short* xnb = (unsigned short*)d_ws;
  unsigned short* Wb =
      (unsigned short*)((char*)d_ws + (size_t)16384 * 2048 * 2);

  ln_wconv_kernel<<<16384 + 4096, 256, 0, stream>>>(x, xnb, W, Wb);
  gemm8p<<<512, 512, 0, stream>>>(xnb, Wb, out);
}

// Round 8
// 178.862 us; speedup vs baseline: 3.8715x; 3.8715x over previous
//
#include <hip/hip_runtime.h>
#include <hip/hip_bf16.h>
#include <stdint.h>

// LNLinearSigmoid: LayerNorm(x) @ W^T -> sigmoid
// Round 8: revert B to LDS staging (R7's per-lane B gathers broke L2/L3).
// GEMM: 256x256 tile, BK=64, 1024 threads / 16 waves (4x4 of 64x64) ->
// acc 64 VGPR/wave -> 4 waves/SIMD latency hiding. Single barrier + counted
// vmcnt per K-tile, dbuf LDS 128KB, zero-conflict XOR swizzle, XCD swizzle.
// ws >= 75.5 MB.

typedef __attribute__((ext_vector_type(4))) float f32x4;
typedef __attribute__((ext_vector_type(8))) __bf16 b16x8;

__device__ __forceinline__ void async16(void* lds_p, const void* g) {
  __builtin_amdgcn_global_load_lds(
      (const __attribute__((address_space(1))) void*)g,
      (__attribute__((address_space(3))) void*)lds_p, 16, 0, 0);
}

__device__ __forceinline__ unsigned short f2bf(float f) {
  uint32_t u = __float_as_uint(f);
  u += 0x7FFFu + ((u >> 16) & 1u);
  return (unsigned short)(u >> 16);
}

// ---------------- LN (blocks 0..16383) + W conv (blocks 16384..20479) ------
__global__ __launch_bounds__(256) void ln_wconv_kernel(
    const float* __restrict__ x, unsigned short* __restrict__ xn,
    const float* __restrict__ W, unsigned short* __restrict__ Wb) {
  const int t = threadIdx.x;
  if (blockIdx.x >= 16384) {
    const size_t i = (size_t)(blockIdx.x - 16384) * 256 + t;
    float4 v = ((const float4*)W)[i];
    ushort4 o;
    o.x = f2bf(v.x); o.y = f2bf(v.y); o.z = f2bf(v.z); o.w = f2bf(v.w);
    ((ushort4*)Wb)[i] = o;
    return;
  }
  const int row = blockIdx.x;
  const float4* xr = (const float4*)(x + (size_t)row * 2048);
  float4 a = xr[t];
  float4 b = xr[t + 256];
  float s = a.x + a.y + a.z + a.w + b.x + b.y + b.z + b.w;
  float q = a.x * a.x + a.y * a.y + a.z * a.z + a.w * a.w +
            b.x * b.x + b.y * b.y + b.z * b.z + b.w * b.w;
#pragma unroll
  for (int off = 32; off > 0; off >>= 1) {
    s += __shfl_down(s, off);
    q += __shfl_down(q, off);
  }
  __shared__ float red[8];
  const int w = t >> 6;
  if ((t & 63) == 0) { red[w] = s; red[4 + w] = q; }
  __syncthreads();
  s = red[0] + red[1] + red[2] + red[3];
  q = red[4] + red[5] + red[6] + red[7];
  const float mean = s * (1.0f / 2048.0f);
  const float var = fmaxf(q * (1.0f / 2048.0f) - mean * mean, 0.0f);
  const float scl = rsqrtf(var + 1e-5f);
  ushort4 o0, o1;
  o0.x = f2bf((a.x - mean) * scl);
  o0.y = f2bf((a.y - mean) * scl);
  o0.z = f2bf((a.z - mean) * scl);
  o0.w = f2bf((a.w - mean) * scl);
  o1.x = f2bf((b.x - mean) * scl);
  o1.y = f2bf((b.y - mean) * scl);
  o1.z = f2bf((b.z - mean) * scl);
  o1.w = f2bf((b.w - mean) * scl);
  ushort4* orow = (ushort4*)(xn + (size_t)row * 2048);
  orow[t] = o0;
  orow[t + 256] = o1;
}

// ---------------- 256x256 GEMM, 16 waves, single-barrier dbuf --------------
// LDS: buf*65536 + {A: 0 (256 rows x 128B), B: 32768}. 1024 threads stage
// 16KB/round -> A: 2 rounds, B: 2 rounds = 4 async16/thread/K-tile.
// Per K-tile: STG(t+1) -> VMC(4) -> reads(S0) -> LGKM0 -> MFMA S0 (16)
// interleaved with reads(S1) -> MFMA S1 (16) -> BARR.
// Wave w: rows wr*64 (wr=w>>2), cols wc*64 (wc=w&3); 4x4 16x16 frags.

#define STG(BOFF, KT)                                                  \
  do {                                                                 \
    const char* sA_ = pA + (size_t)(KT) * 128;                         \
    const char* sB_ = pB + (size_t)(KT) * 128;                         \
    char* d_ = lds + (BOFF) + tid * 16;                                \
    async16(d_, sA_);                                                  \
    async16(d_ + 16384, sA_ + (size_t)128 * 4096);                     \
    async16(d_ + 32768, sB_);                                          \
    async16(d_ + 49152, sB_ + (size_t)128 * 4096);                     \
  } while (0)

#define LDA_S(BOFF, S)                                                 \
  do {                                                                 \
    _Pragma("unroll") for (int i_ = 0; i_ < 4; ++i_) {                 \
      const char* p_ = lds + (BOFF) + abase + i_ * 2048;               \
      aF[i_][S] = *(const b16x8*)(p_ + ((S) ? cs1 : cs0));             \
    }                                                                  \
  } while (0)

#define LDB_S(BOFF, S)                                                 \
  do {                                                                 \
    _Pragma("unroll") for (int j_ = 0; j_ < 4; ++j_) {                 \
      const char* p_ = lds + (BOFF) + bbase + j_ * 2048;               \
      bF[j_][S] = *(const b16x8*)(p_ + ((S) ? cs1 : cs0));             \
    }                                                                  \
  } while (0)

#define MFMA_IJ(ILO, IHI, S)                                           \
  do {                                                                 \
    __builtin_amdgcn_s_setprio(1);                                     \
    _Pragma("unroll") for (int i_ = (ILO); i_ < (IHI); ++i_) {         \
      _Pragma("unroll") for (int j_ = 0; j_ < 4; ++j_) {               \
        acc[i_][j_] = __builtin_amdgcn_mfma_f32_16x16x32_bf16(         \
            aF[i_][S], bF[j_][S], acc[i_][j_], 0, 0, 0);               \
      }                                                                \
    }                                                                  \
    __builtin_amdgcn_s_setprio(0);                                     \
  } while (0)

#define BARR                                                           \
  do {                                                                 \
    __builtin_amdgcn_s_barrier();                                      \
    asm volatile("" ::: "memory");                                     \
  } while (0)

#define LGKM0                                                          \
  do {                                                                 \
    asm volatile("s_waitcnt lgkmcnt(0)" ::: "memory");                 \
    __builtin_amdgcn_sched_barrier(0);                                 \
  } while (0)

#define SB0 __builtin_amdgcn_sched_barrier(0)
#define VMC(n) asm volatile("s_waitcnt vmcnt(" #n ")" ::: "memory")

__global__ __launch_bounds__(1024, 4) void gemm16w(
    const unsigned short* __restrict__ A, const unsigned short* __restrict__ B,
    float* __restrict__ C) {
  __shared__ __align__(16) char lds[131072];

  const int bid0 = blockIdx.x;                       // 512 blocks
  const int bid = (bid0 & 7) * 64 + (bid0 >> 3);     // XCD swizzle (512%8==0)
  const int bm = bid >> 3;                           // 0..63
  const int bn = bid & 7;                            // 0..7

  const int tid = threadIdx.x;
  const int w = tid >> 6, l = tid & 63;
  const int wr = w >> 2, wc = w & 3;                 // 4x4 wave grid
  const int fr = l & 15, fg = l >> 4;

  // staging source (linear LDS dest, inverse-swizzled global source)
  const int arow = tid >> 3;                              // 0..127
  const int swz = ((tid & 7) << 4) ^ ((arow & 7) << 4);
  const char* pA = (const char*)A + (size_t)(bm * 256 + arow) * 4096 + swz;
  const char* pB = (const char*)B + (size_t)(bn * 256 + arow) * 4096 + swz;

  // ds_read offsets (proven zero-conflict swizzle)
  const int cswz = (fg << 4) ^ ((fr & 7) << 4);
  const int cs0 = cswz, cs1 = cswz ^ 64;
  const int abase = (wr * 64 + fr) * 128;
  const int bbase = 32768 + (wc * 64 + fr) * 128;

  f32x4 acc[4][4] = {};
  b16x8 aF[4][2], bF[4][2];

  // prologue: stage t0 -> buf0
  STG(0, 0);
  VMC(0);
  BARR;

#pragma unroll 1
  for (int t = 0; t < 32; ++t) {
    const int cur = (t & 1) * 65536;
    const int nxt = 65536 - cur;

    if (t < 31) { STG(nxt, t + 1); VMC(4); } else { VMC(0); }
    SB0;
    LDA_S(cur, 0); LDB_S(cur, 0);
    LGKM0;
    MFMA_IJ(0, 2, 0);                    // 8 MFMA (i=0,1; S0)
    SB0; LDA_S(cur, 1); LDB_S(cur, 1); SB0;
    MFMA_IJ(2, 4, 0);                    // 8 MFMA (i=2,3; S0)
    LGKM0;
    MFMA_IJ(0, 4, 1);                    // 16 MFMA (S1)
    BARR;
  }

  // epilogue: sigmoid + store. C/D frag: row = fg*4 + r, col = fr.
  float* gC = C + (size_t)(bm * 256 + wr * 64) * 2048 + bn * 256 + wc * 64;
#pragma unroll
  for (int i = 0; i < 4; ++i) {
#pragma unroll
    for (int j = 0; j < 4; ++j) {
#pragma unroll
      for (int r = 0; r < 4; ++r) {
        const int row = i * 16 + fg * 4 + r;
        const int col = j * 16 + fr;
        const float y = acc[i][j][r];
        gC[(size_t)row * 2048 + col] =
            __builtin_amdgcn_rcpf(1.0f + __expf(-y));
      }
    }
  }
}

extern "C" void kernel_launch(void* const* d_in, const int* in_sizes, int n_in,
                              void* d_out, int out_size, void* d_ws, size_t ws_size,
                              hipStream_t stream) {
  const float* x = (const float*)d_in[0];
  const float* W = (const float*)d_in[1];
  float* out = (float*)d_out;

  unsigned short* xnb = (unsigned short*)d_ws;
  unsigned short* Wb =
      (unsigned short*)((char*)d_ws + (size_t)16384 * 2048 * 2);

  ln_wconv_kernel<<<16384 + 4096, 256, 0, stream>>>(x, xnb, W, Wb);
  gemm16w<<<512, 1024, 0, stream>>>(xnb, Wb, out);
}